// Round 1
// baseline (1078.100 us; speedup 1.0000x reference)
//
#include <hip/hip_runtime.h>

// ---------- types ----------
typedef __attribute__((ext_vector_type(8))) short short8;   // 8 bf16 (4 VGPRs)
typedef __attribute__((ext_vector_type(4))) float f32x4;    // MFMA accumulator

__device__ __forceinline__ unsigned short f2bf(float f) {
  union { float f; unsigned u; } x{f};
  unsigned r = x.u + 0x7FFFu + ((x.u >> 16) & 1u);  // round-to-nearest-even
  return (unsigned short)(r >> 16);
}

// async global->LDS, 16B per lane; LDS dest is wave-uniform base + lane*16
__device__ __forceinline__ void gload_lds16(const void* g, void* l) {
  __builtin_amdgcn_global_load_lds(
      (__attribute__((address_space(1))) void*)((unsigned long long)g),
      (__attribute__((address_space(3))) void*)(unsigned)((unsigned long long)l),
      16, 0, 0);
}

// ---------- K1: trellis decode -> W[4096][4096] fp32 ----------
// tile = o_tile*256 + i_tile ; t = (o&15)*16 + (i&15) ; s = t>>1, v = t&1
// nib(s) = (word[s>>2] >> (12-4*(s&3))) & 0xF
// state(s) = nib(s) | nib(s-1)<<4 | nib(s-2)<<8 | nib(s-3)<<12   (mod 128, tail-biting)
__global__ void k_dequant(const int* __restrict__ trellis,
                          const float* __restrict__ tlut,
                          float* __restrict__ W) {
  __shared__ unsigned short words[64];       // 2 tiles * 32 words
  const int t = threadIdx.x;
  if (t < 64) words[t] = (unsigned short)(trellis[(size_t)blockIdx.x * 64 + t] & 0xFFFF);
  __syncthreads();
  const int tl = t >> 7;                     // local tile 0/1
  const int s  = t & 127;
  const unsigned short* w = &words[tl * 32];
  unsigned state = 0;
#pragma unroll
  for (int j = 0; j < 4; ++j) {
    const int ss = (s - j) & 127;
    const unsigned nb = ((unsigned)w[ss >> 2] >> (12 - 4 * (ss & 3))) & 0xFu;
    state |= nb << (4 * j);
  }
  const float2 v = *(const float2*)(tlut + (size_t)state * 2);
  const int tile = blockIdx.x * 2 + tl;
  const int o = ((tile >> 8) << 4) + (s >> 3);
  const int i = ((tile & 255) << 4) + ((s & 7) << 1);
  *(float2*)(W + (size_t)o * 4096 + i) = v;
}

// ---------- K2: FWHT over rows (last axis), in place, * 1/64 ----------
__global__ void k_fwht_row(float* __restrict__ W) {
  __shared__ float row[4096];
  const int t = threadIdx.x;
  float* g = W + ((size_t)blockIdx.x << 12);
#pragma unroll
  for (int k = 0; k < 4; ++k) {
    const int e = (t + (k << 8)) << 2;
    *(float4*)(row + e) = *(const float4*)(g + e);
  }
  __syncthreads();
  for (int h = 1; h < 4096; h <<= 1) {
#pragma unroll
    for (int k = 0; k < 8; ++k) {
      const int p  = t + (k << 8);
      const int j1 = ((p & ~(h - 1)) << 1) | (p & (h - 1));
      const int j2 = j1 + h;
      const float a = row[j1], b = row[j2];
      row[j1] = a + b;
      row[j2] = a - b;
    }
    __syncthreads();
  }
#pragma unroll
  for (int k = 0; k < 4; ++k) {
    const int e = (t + (k << 8)) << 2;
    float4 v = *(float4*)(row + e);
    v.x *= 0.015625f; v.y *= 0.015625f; v.z *= 0.015625f; v.w *= 0.015625f;
    *(float4*)(g + e) = v;
  }
}

// 6-stage H64 butterfly over the first index of tile[64][64]
__device__ __forceinline__ void butterfly64(float (*tile)[64], int t) {
  const int c  = t & 63;
  const int pb = t >> 6;
#pragma unroll
  for (int h = 1; h < 64; h <<= 1) {
#pragma unroll
    for (int k = 0; k < 8; ++k) {
      const int p  = pb + (k << 2);
      const int j1 = ((p & ~(h - 1)) << 1) | (p & (h - 1));
      const int j2 = j1 + h;
      const float a = tile[j1][c], b = tile[j2][c];
      tile[j1][c] = a + b;
      tile[j2][c] = a - b;
    }
    __syncthreads();
  }
}

// ---------- K3a: column FWHT, low 6 bits of row index (contiguous 64-row groups) ----------
__global__ void k_fwht_col1(float* __restrict__ W) {
  __shared__ float tile[64][64];
  const int t  = threadIdx.x;
  const int rg = blockIdx.x >> 6;
  const int cg = blockIdx.x & 63;
  const size_t base = ((size_t)rg << 6) * 4096 + ((size_t)cg << 6);
#pragma unroll
  for (int k = 0; k < 4; ++k) {
    const int idx = t + (k << 8);
    const int r = idx >> 4, c4 = idx & 15;
    *(float4*)(&tile[r][c4 << 2]) = *(const float4*)(W + base + (size_t)r * 4096 + (c4 << 2));
  }
  __syncthreads();
  butterfly64(tile, t);
#pragma unroll
  for (int k = 0; k < 4; ++k) {
    const int idx = t + (k << 8);
    const int r = idx >> 4, c4 = idx & 15;
    *(float4*)(W + base + (size_t)r * 4096 + (c4 << 2)) = *(float4*)(&tile[r][c4 << 2]);
  }
}

// ---------- K3b: column FWHT, high 6 bits (rows b, b+64, ...), *1/64, *SV[o]*SU[i], -> bf16 Mt[N][K] ----------
__global__ void k_fwht_col2(const float* __restrict__ W,
                            const float* __restrict__ SU,
                            const float* __restrict__ SV,
                            unsigned short* __restrict__ Mt) {
  __shared__ float tile[64][64];
  const int t  = threadIdx.x;
  const int b  = blockIdx.x >> 6;   // row residue (low bits)
  const int cg = blockIdx.x & 63;
#pragma unroll
  for (int k = 0; k < 4; ++k) {
    const int idx = t + (k << 8);
    const int a = idx >> 4, c4 = idx & 15;
    const int row = (a << 6) + b;
    *(float4*)(&tile[a][c4 << 2]) =
        *(const float4*)(W + (size_t)row * 4096 + ((size_t)cg << 6) + (c4 << 2));
  }
  __syncthreads();
  butterfly64(tile, t);
#pragma unroll
  for (int k = 0; k < 4; ++k) {
    const int idx = t + (k << 8);
    const int a = idx >> 4, c4 = idx & 15;
    const int row = (a << 6) + b;                 // o (OUT index)
    const int col0 = (cg << 6) + (c4 << 2);       // i (IN index)
    const float sv = SV[row] * 0.015625f;
    const float4 su = *(const float4*)(SU + col0);
    const float4 v = *(float4*)(&tile[a][c4 << 2]);
    ushort4 o;
    o.x = f2bf(v.x * sv * su.x);
    o.y = f2bf(v.y * sv * su.y);
    o.z = f2bf(v.z * sv * su.z);
    o.w = f2bf(v.w * sv * su.w);
    *(ushort4*)(Mt + (size_t)row * 4096 + col0) = o;
  }
}

// ---------- K5: x fp32 -> bf16 ----------
__global__ void k_cvt_x(const float* __restrict__ x, unsigned short* __restrict__ xb) {
  const long long n4 = (long long)16384 * 4096 / 4;
  long long i = (long long)blockIdx.x * blockDim.x + threadIdx.x;
  const long long stride = (long long)gridDim.x * blockDim.x;
  for (; i < n4; i += stride) {
    const float4 v = *(const float4*)(x + i * 4);
    ushort4 o;
    o.x = f2bf(v.x); o.y = f2bf(v.y); o.z = f2bf(v.z); o.w = f2bf(v.w);
    *(ushort4*)(xb + i * 4) = o;
  }
}

// ---------- K6: GEMM C[16384,4096] = A[16384,4096](bf16) * Mt[4096,4096](bf16, [N][K])^T ----------
// m97 structure: 128x128 tile, BK=32, 4 waves (2x2), 64x64 per wave, 16x16x32 MFMA,
// global_load_lds width 16, 2 barriers per K-step.
__global__ void __launch_bounds__(256) k_gemm(const unsigned short* __restrict__ A,
                                              const unsigned short* __restrict__ B,
                                              float* __restrict__ C) {
  __shared__ unsigned short Asm[128 * 32];  // 8 KB
  __shared__ unsigned short Bsm[128 * 32];  // 8 KB
  const int t    = threadIdx.x;
  const int w    = t >> 6, lane = t & 63;
  const int wr   = w >> 1, wc = w & 1;
  const int lr   = lane & 15, lk = lane >> 4;
  const int bid  = blockIdx.x;
  const int nt   = bid & 31;   // nt fastest: 32 consecutive blocks share the A panel
  const int mt   = bid >> 5;

  // staging map: thread t -> row t>>2 (and +64), 8 bf16 at col (t&3)*8
  const unsigned short* aptr = A + (((size_t)(mt * 128 + (t >> 2))) << 12) + ((t & 3) << 3);
  const unsigned short* bptr = B + (((size_t)(nt * 128 + (t >> 2))) << 12) + ((t & 3) << 3);
  unsigned short* AsmW = Asm + w * 512;   // wave-uniform LDS base (bytes w*1024)
  unsigned short* BsmW = Bsm + w * 512;

  f32x4 acc[4][4];
#pragma unroll
  for (int i = 0; i < 4; ++i)
#pragma unroll
    for (int j = 0; j < 4; ++j) acc[i][j] = (f32x4){0.f, 0.f, 0.f, 0.f};

  for (int kk = 0; kk < 4096; kk += 32) {
    __syncthreads();                       // previous compute done before overwrite
    gload_lds16(aptr,                 AsmW);
    gload_lds16(aptr + (64ull << 12), AsmW + 2048);
    gload_lds16(bptr,                 BsmW);
    gload_lds16(bptr + (64ull << 12), BsmW + 2048);
    aptr += 32;
    bptr += 32;
    __syncthreads();                       // vmcnt(0) drained by compiler before barrier

    short8 af[4], bf[4];
#pragma unroll
    for (int mi = 0; mi < 4; ++mi)
      af[mi] = *(const short8*)(Asm + (wr * 64 + mi * 16 + lr) * 32 + lk * 8);
#pragma unroll
    for (int ni = 0; ni < 4; ++ni)
      bf[ni] = *(const short8*)(Bsm + (wc * 64 + ni * 16 + lr) * 32 + lk * 8);
#pragma unroll
    for (int mi = 0; mi < 4; ++mi)
#pragma unroll
      for (int ni = 0; ni < 4; ++ni)
        acc[mi][ni] = __builtin_amdgcn_mfma_f32_16x16x32_bf16(af[mi], bf[ni], acc[mi][ni], 0, 0, 0);
  }

  // C/D layout: col = lane&15, row = (lane>>4)*4 + reg
  float* cbase = C + (((size_t)(mt * 128 + wr * 64 + lk * 4)) << 12) + nt * 128 + wc * 64 + lr;
#pragma unroll
  for (int mi = 0; mi < 4; ++mi)
#pragma unroll
    for (int ni = 0; ni < 4; ++ni)
#pragma unroll
      for (int r = 0; r < 4; ++r)
        cbase[(((size_t)(mi * 16 + r)) << 12) + ni * 16] = acc[mi][ni][r];
}

extern "C" void kernel_launch(void* const* d_in, const int* in_sizes, int n_in,
                              void* d_out, int out_size, void* d_ws, size_t ws_size,
                              hipStream_t stream) {
  const float* x       = (const float*)d_in[0];   // (8,2048,4096) fp32
  const int*   trellis = (const int*)d_in[1];     // (65536,32) int32
  const float* tlut    = (const float*)d_in[2];   // (65536,2) fp32
  const float* SU      = (const float*)d_in[3];   // (4096,)
  const float* SV      = (const float*)d_in[4];   // (4096,)
  float* out = (float*)d_out;

  char* ws = (char*)d_ws;
  float*          W  = (float*)ws;                           // 64 MiB fp32
  unsigned short* Mt = (unsigned short*)(ws + (64ull << 20)); // 32 MiB bf16 [N][K]
  unsigned short* xb = (unsigned short*)(ws + (96ull << 20)); // 128 MiB bf16 [M][K]

  hipLaunchKernelGGL(k_dequant,   dim3(32768), dim3(256), 0, stream, trellis, tlut, W);
  hipLaunchKernelGGL(k_fwht_row,  dim3(4096),  dim3(256), 0, stream, W);
  hipLaunchKernelGGL(k_fwht_col1, dim3(4096),  dim3(256), 0, stream, W);
  hipLaunchKernelGGL(k_fwht_col2, dim3(4096),  dim3(256), 0, stream, W, SU, SV, Mt);
  hipLaunchKernelGGL(k_cvt_x,     dim3(2048),  dim3(256), 0, stream, x, xb);
  hipLaunchKernelGGL(k_gemm,      dim3(4096),  dim3(256), 0, stream, xb, Mt, out);
}